// Round 8
// baseline (2971.860 us; speedup 1.0000x reference)
//
#include <hip/hip_runtime.h>
#include <cstdint>

// ---------------------------------------------------------------------------
// GCN: 3x GCNConv(+ELU) + linear head.
// Structure:
//  - 256-node dst-buckets (391). Build: hist -> scan -> LDS-tile scatter
//    (bucket-grouped bedge) -> bucket_finish (deg/dinv + 8-way
//    (quarter x sub-bucket) split of each bucket region into perm).
//  - Aggregation: per-128-node-sub-bucket block, accumulator in LDS
//    (padded rows, ds_add_f32 atomics), gathers xw[src] with norm computed
//    on the fly. One launch per src-quarter phase -> every resident block
//    gathers from the same <=3.2MB xw slice (fits 4MB per-XCD L2).
//  - A(XW) = (AX)W associativity: gather passes run at F=16,16,32.
// ---------------------------------------------------------------------------

__device__ inline int2 ldnt2(const int2* p) {
    long long v = __builtin_nontemporal_load((const long long*)p);
    int2 r;
    r.x = (int)(unsigned)(v & 0xFFFFFFFFLL);
    r.y = (int)(unsigned)((unsigned long long)v >> 32);
    return r;
}

typedef float __attribute__((ext_vector_type(4))) f4v;
__device__ inline float4 ldnt4(const float4* p) {
    f4v v = __builtin_nontemporal_load((const f4v*)p);
    float4 r;
    r.x = v.x; r.y = v.y; r.z = v.z; r.w = v.w;
    return r;
}

__device__ inline int quarter_of(int s, int qs) {
    return (s >= qs) + (s >= 2 * qs) + (s >= 3 * qs);
}

// ---- Pass A: per-bucket edge counts. bucket = dst >> 8 (256 nodes).
__global__ void __launch_bounds__(256) bucket_hist(const int* __restrict__ dst,
                                                   int* __restrict__ bcnt,
                                                   int E, int chunk) {
    __shared__ int h[512];
    for (int i = threadIdx.x; i < 512; i += 256) h[i] = 0;
    __syncthreads();
    int c0 = blockIdx.x * chunk;
    int c1 = min(E, c0 + chunk);
    for (int i = c0 + threadIdx.x; i < c1; i += 256)
        atomicAdd(&h[((unsigned)dst[i]) >> 8], 1);
    __syncthreads();
    for (int i = threadIdx.x; i < 512; i += 256)
        if (h[i]) atomicAdd(&bcnt[i], h[i]);
}

// ---- Pass B: scan 512 bins -> boff[513], gcur.
__global__ void __launch_bounds__(512) bucket_scan(const int* __restrict__ bcnt,
                                                   int* __restrict__ boff,
                                                   int* __restrict__ gcur) {
    __shared__ int part[512];
    int t = threadIdx.x;
    int c = bcnt[t];
    part[t] = c;
    __syncthreads();
    for (int off = 1; off < 512; off <<= 1) {
        int v = part[t];
        int a = (t >= off) ? part[t - off] : 0;
        __syncthreads();
        part[t] = v + a;
        __syncthreads();
    }
    int excl = part[t] - c;
    boff[t] = excl;
    gcur[t] = excl;
    if (t == 511) boff[512] = part[511];
}

// ---- Pass C: LDS counting-sort of 4096-edge tiles into bucket regions.
// pack: (local_dst(8b) << 24) | src(24b)
__global__ void __launch_bounds__(512) bucket_scatter(const int* __restrict__ src,
                                                      const int* __restrict__ dst,
                                                      const float* __restrict__ w,
                                                      int* __restrict__ gcur,
                                                      int2* __restrict__ bedge,
                                                      int E) {
    constexpr int TILE = 4096;
    __shared__ int hc[512];     // histogram, then cursor
    __shared__ int gb[512];
    __shared__ int part[512];
    __shared__ int2 sedge[TILE];
    __shared__ unsigned short sbuck[TILE];

    int t = threadIdx.x;
    int c0 = blockIdx.x * TILE;
    int mtile = min(TILE, E - c0);

    hc[t] = 0;
    __syncthreads();

    int  my_d[8];
    int  my_s[8];
    float my_w[8];
#pragma unroll
    for (int k = 0; k < 2; ++k) {
        int e0 = c0 + (t + k * 512) * 4;
        if (e0 + 4 <= E) {
            int4 d4 = *(const int4*)(dst + e0);
            int4 s4 = *(const int4*)(src + e0);
            float4 w4 = *(const float4*)(w + e0);
            my_d[k*4+0]=d4.x; my_d[k*4+1]=d4.y; my_d[k*4+2]=d4.z; my_d[k*4+3]=d4.w;
            my_s[k*4+0]=s4.x; my_s[k*4+1]=s4.y; my_s[k*4+2]=s4.z; my_s[k*4+3]=s4.w;
            my_w[k*4+0]=w4.x; my_w[k*4+1]=w4.y; my_w[k*4+2]=w4.z; my_w[k*4+3]=w4.w;
        } else {
#pragma unroll
            for (int j = 0; j < 4; ++j) {
                int e = e0 + j;
                bool ok = e < E;
                my_d[k*4+j] = ok ? dst[e] : -1;
                my_s[k*4+j] = ok ? src[e] : 0;
                my_w[k*4+j] = ok ? w[e] : 0.f;
            }
        }
    }
#pragma unroll
    for (int j = 0; j < 8; ++j)
        if (my_d[j] >= 0) atomicAdd(&hc[((unsigned)my_d[j]) >> 8], 1);
    __syncthreads();

    int hb = hc[t];
    part[t] = hb;
    __syncthreads();
    for (int off = 1; off < 512; off <<= 1) {
        int v = part[t];
        int a = (t >= off) ? part[t - off] : 0;
        __syncthreads();
        part[t] = v + a;
        __syncthreads();
    }
    int excl = part[t] - hb;
    hc[t] = excl;                                   // cursor = local offset
    gb[t] = hb ? (atomicAdd(&gcur[t], hb) - excl) : 0;
    __syncthreads();

#pragma unroll
    for (int j = 0; j < 8; ++j) {
        int d = my_d[j];
        if (d < 0) continue;
        unsigned ud = (unsigned)d;
        int b = ud >> 8;
        int p = atomicAdd(&hc[b], 1);
        sedge[p] = make_int2((int)(((ud & 255u) << 24) | (unsigned)my_s[j]),
                             __float_as_int(my_w[j]));
        sbuck[p] = (unsigned short)b;
    }
    __syncthreads();

    for (int i = t; i < mtile; i += 512) {
        int b = sbuck[i];
        bedge[gb[b] + i] = sedge[i];
    }
}

// ---- Pass D: per-bucket deg -> dinv ; 8-way (quarter x sub) split -> perm.
// Segment order within bucket: idx = quarter*2 + sub (sub = local_dst>>7).
__global__ void __launch_bounds__(1024) bucket_finish(const int* __restrict__ boff,
                                                      const int2* __restrict__ bedge,
                                                      float* __restrict__ dinv,
                                                      int2* __restrict__ perm,
                                                      int* __restrict__ qrp,
                                                      int N, int qs) {
    __shared__ float deg[256];
    __shared__ int qc[8];
    __shared__ int ofs[8];
    int b = blockIdx.x;
    int base = boff[b];
    int m = boff[b + 1] - base;
    int t = threadIdx.x;
    if (t < 256) deg[t] = 0.f;
    if (t < 8) qc[t] = 0;
    __syncthreads();

    for (int i = t; i < m; i += 1024) {
        int2 e = bedge[base + i];
        unsigned ux = (unsigned)e.x;
        int l = (int)(ux >> 24);
        int s = (int)(ux & 0xFFFFFFu);
        atomicAdd(&deg[l], __int_as_float(e.y));
        atomicAdd(&qc[quarter_of(s, qs) * 2 + (l >> 7)], 1);
    }
    __syncthreads();

    if (t == 0) {
        int r = 0;
#pragma unroll
        for (int i = 0; i < 8; ++i) { ofs[i] = r; r += qc[i]; }
    }
    int node = b * 256 + t;
    if (t < 256 && node < N) dinv[node] = rsqrtf(deg[t] + 1.0f);
    __syncthreads();

    if (t < 8) {
        qrp[b * 8 + t] = base + ofs[t];
        qc[t] = ofs[t];                  // reuse as cursor
    }
    __syncthreads();

    for (int i = t; i < m; i += 1024) {  // bucket run is L2-hot from sweep 1
        int2 e = bedge[base + i];
        unsigned ux = (unsigned)e.x;
        int l = (int)(ux >> 24);
        int s = (int)(ux & 0xFFFFFFu);
        int idx = quarter_of(s, qs) * 2 + (l >> 7);
        int p = atomicAdd(&qc[idx], 1);
        perm[base + p] = e;
    }
}

// x[N,256] @ W[256,16] -> xw[N,16].
__global__ void __launch_bounds__(256) gemm_x16(const float* __restrict__ x,
                                                const float* __restrict__ W,
                                                float* __restrict__ xw, int N) {
    __shared__ float Ws[256 * 16];
    for (int i = threadIdx.x; i < 256 * 16; i += 256) Ws[i] = W[i];
    __syncthreads();
    int c = threadIdx.x & 15;
    int rl = threadIdx.x >> 4;
    int r = blockIdx.x * 16 + rl;
    if (r >= N) return;
    const float4* x4 = (const float4*)(x + (size_t)r * 256);
    float acc = 0.f;
#pragma unroll 8
    for (int k4 = 0; k4 < 64; ++k4) {
        float4 v = ldnt4(x4 + k4);
        const float* wr = &Ws[k4 * 64 + c];
        acc += v.x * wr[0] + v.y * wr[16] + v.z * wr[32] + v.w * wr[48];
    }
    xw[(size_t)r * 16 + c] = acc;
}

// in[N,K] @ W[K,F] + bias -> out[N,F], optional ELU on output.
template <int K, int F, bool OUT_ELU>
__global__ void __launch_bounds__(256) gemm_small(const float* __restrict__ in,
                                                  const float* __restrict__ W,
                                                  const float* __restrict__ bias,
                                                  float* __restrict__ out, int N) {
    constexpr int ROWS = 256 / F;
    __shared__ float Ws[K * F];
    __shared__ float Is[ROWS * K];
    for (int i = threadIdx.x; i < K * F; i += 256) Ws[i] = W[i];
    int r0 = blockIdx.x * ROWS;
    for (int i = threadIdx.x; i < ROWS * K; i += 256)
        Is[i] = in[(size_t)r0 * K + i];
    __syncthreads();
    int c = threadIdx.x % F;
    int rl = threadIdx.x / F;
    float acc = bias[c];
#pragma unroll
    for (int k = 0; k < K; ++k) acc += Is[rl * K + k] * Ws[k * F + c];
    if (OUT_ELU) acc = acc > 0.f ? acc : expm1f(acc);
    out[(size_t)(r0 + rl) * F + c] = acc;
}

// ---- Quarter-phased LDS-accumulator aggregation.
// Block = 128-node sub-bucket. flags: bit0 = init (self-loop [+bias]),
// bit1 = final (apply ELU if template ELU). One launch per phase.
template <int F, int S, bool ELU>
__global__ void __launch_bounds__(512) agg_phase(const int* __restrict__ boff,
                                                 const int* __restrict__ qrp,
                                                 const int2* __restrict__ perm,
                                                 const float* __restrict__ xw,
                                                 const float* __restrict__ dinv,
                                                 const float* __restrict__ bias,
                                                 float* __restrict__ out,
                                                 int N, int q0, int flags) {
    constexpr int G = F / 4;
    constexpr int PAD = F + 1;          // odd stride -> bank spread
    __shared__ float acc[128 * PAD];
    __shared__ float sdv[128];
    int bid = blockIdx.x;
    int b = bid >> 1;
    int sub = bid & 1;
    int nb = bid * 128;
    int t = threadIdx.x;
    if (t < 128) sdv[t] = (nb + t < N) ? dinv[nb + t] : 0.f;
    __syncthreads();

    if (flags & 1) {
        for (int i = t; i < 128 * F; i += 512) {
            int n = i / F, c = i - n * F;
            int gn = nb + n;
            float v = 0.f;
            if (gn < N) {
                float d = sdv[n];
                v = d * d * xw[(size_t)gn * F + c];
                if (bias) v += bias[c];
            }
            acc[n * PAD + c] = v;
        }
    } else {
        for (int i = t; i < 128 * F; i += 512) {
            int n = i / F, c = i - n * F;
            int gn = nb + n;
            acc[n * PAD + c] = (gn < N) ? out[(size_t)gn * F + c] : 0.f;
        }
    }
    __syncthreads();

    const float4* xw4 = (const float4*)xw;
    int gid = t / G;
    int lq = t - gid * G;
    constexpr int NG = 512 / G;
#pragma unroll
    for (int ss = 0; ss < S; ++ss) {
        int idx = (q0 + ss) * 2 + sub;
        int jb = qrp[b * 8 + idx];
        int je = (idx == 7) ? boff[b + 1] : qrp[b * 8 + idx + 1];
        for (int j = jb + gid; j < je; j += NG) {
            int2 e = ldnt2(perm + j);
            unsigned ux = (unsigned)e.x;
            int l = (int)(ux >> 24) - sub * 128;
            int s = (int)(ux & 0xFFFFFFu);
            float nm = dinv[s] * __int_as_float(e.y) * sdv[l];
            float4 v = xw4[(size_t)s * G + lq];
            float* ap = &acc[l * PAD + lq * 4];
            atomicAdd(ap + 0, nm * v.x);
            atomicAdd(ap + 1, nm * v.y);
            atomicAdd(ap + 2, nm * v.z);
            atomicAdd(ap + 3, nm * v.w);
        }
    }
    __syncthreads();

    for (int i = t; i < 128 * F; i += 512) {
        int n = i / F, c = i - n * F;
        int gn = nb + n;
        if (gn >= N) continue;
        float r = acc[n * PAD + c];
        if (ELU && (flags & 2)) r = r > 0.f ? r : expm1f(r);
        out[(size_t)gn * F + c] = r;
    }
}

extern "C" void kernel_launch(void* const* d_in, const int* in_sizes, int n_in,
                              void* d_out, int out_size, void* d_ws, size_t ws_size,
                              hipStream_t stream) {
    const float* x  = (const float*)d_in[0];
    const int*   ei = (const int*)d_in[1];
    const float* w  = (const float*)d_in[2];
    const float* W0 = (const float*)d_in[3];
    const float* b0 = (const float*)d_in[4];
    const float* W1 = (const float*)d_in[5];
    const float* b1 = (const float*)d_in[6];
    const float* W2 = (const float*)d_in[7];
    const float* b2 = (const float*)d_in[8];
    const float* Wm = (const float*)d_in[9];
    const float* bm = (const float*)d_in[10];
    float* out = (float*)d_out;

    const int N = in_sizes[0] / 256;
    const int E = in_sizes[2];
    const int* src = ei;
    const int* dst = ei + E;
    const int nbuck = (N + 255) >> 8;      // 256-node buckets (<=512)
    const int qs = (N + 3) / 4;            // src-quarter size

    char* ws = (char*)d_ws;
    size_t off = 0;
    auto alloc = [&](size_t bytes) {
        void* p = ws + off;
        off = (off + bytes + 255) & ~(size_t)255;
        return p;
    };
    float* dinv  = (float*)alloc((size_t)N * 4);
    int*   bcnt  = (int*)alloc(520 * 4);
    int*   boff  = (int*)alloc(520 * 4);
    int*   gcur  = (int*)alloc(520 * 4);
    int*   qrp   = (int*)alloc((size_t)nbuck * 8 * 4);
    int2*  bedge = (int2*)alloc((size_t)E * 8);
    int2*  perm  = (int2*)alloc((size_t)E * 8);
    float* BUF_A = (float*)alloc((size_t)N * 32 * 4);
    float* BUF_B = (float*)alloc((size_t)N * 32 * 4);

    hipMemsetAsync(bcnt, 0, 512 * 4, stream);

    // ---- build bucket-grouped, quarter-split edge structure
    bucket_hist<<<(E + 8191) / 8192, 256, 0, stream>>>(dst, bcnt, E, 8192);
    bucket_scan<<<1, 512, 0, stream>>>(bcnt, boff, gcur);
    bucket_scatter<<<(E + 4095) / 4096, 512, 0, stream>>>(src, dst, w, gcur, bedge, E);
    bucket_finish<<<nbuck, 1024, 0, stream>>>(boff, bedge, dinv, perm, qrp, N, qs);

    const int AGB = 2 * nbuck;

    // ---- layer 0: XW = x@W0 ; h1 = elu(A.XW + b0)   [2 phases x 2 quarters]
    gemm_x16<<<(N + 15) / 16, 256, 0, stream>>>(x, W0, BUF_A, N);
    agg_phase<16, 2, true><<<AGB, 512, 0, stream>>>(boff, qrp, perm, BUF_A, dinv, b0, BUF_B, N, 0, 1);
    agg_phase<16, 2, true><<<AGB, 512, 0, stream>>>(boff, qrp, perm, BUF_A, dinv, b0, BUF_B, N, 2, 2);

    // ---- layer 1: AG1 = A.h1 ; h2 = elu(AG1@W1 + b1)
    agg_phase<16, 2, false><<<AGB, 512, 0, stream>>>(boff, qrp, perm, BUF_B, dinv, nullptr, BUF_A, N, 0, 1);
    agg_phase<16, 2, false><<<AGB, 512, 0, stream>>>(boff, qrp, perm, BUF_B, dinv, nullptr, BUF_A, N, 2, 0);
    gemm_small<16, 32, true><<<(N + 7) / 8, 256, 0, stream>>>(BUF_A, W1, b1, BUF_B, N);

    // ---- layer 2: AG2 = A.h2 ; h3 = elu(AG2@W2 + b2)  [4 phases x 1 quarter]
    agg_phase<32, 1, false><<<AGB, 512, 0, stream>>>(boff, qrp, perm, BUF_B, dinv, nullptr, BUF_A, N, 0, 1);
    agg_phase<32, 1, false><<<AGB, 512, 0, stream>>>(boff, qrp, perm, BUF_B, dinv, nullptr, BUF_A, N, 1, 0);
    agg_phase<32, 1, false><<<AGB, 512, 0, stream>>>(boff, qrp, perm, BUF_B, dinv, nullptr, BUF_A, N, 2, 0);
    agg_phase<32, 1, false><<<AGB, 512, 0, stream>>>(boff, qrp, perm, BUF_B, dinv, nullptr, BUF_A, N, 3, 0);
    gemm_small<32, 32, true><<<(N + 7) / 8, 256, 0, stream>>>(BUF_A, W2, b2, BUF_B, N);

    // ---- head: out = h3@Wm + bm
    gemm_small<32, 16, false><<<(N + 15) / 16, 256, 0, stream>>>(BUF_B, Wm, bm, out, N);
}

// Round 9
// 731.892 us; speedup vs baseline: 4.0605x; 4.0605x over previous
//
#include <hip/hip_runtime.h>
#include <cstdint>

// ---------------------------------------------------------------------------
// GCN: 3x GCNConv(+ELU) + linear head.
// perm is ordered (src-quarter, dst-bucket, dst-node); rpq[q][node] is a
// per-quarter CSR. Aggregation = register-accumulator gather over one or two
// quarters PER LAUNCH -> all resident blocks gather from the same <=3.2MB xw
// slice (fits 4MB per-XCD L2). A(XW)=(AX)W: gather passes run at F=16,16,32.
// Build: hist -> scan -> LDS-tile scatter (bucket-grouped bedge) ->
//   bucket_stats (deg/dinv + per-(node,quarter) counts -> cntg, bq) ->
//   qscan ((q,bucket) global bases) ->
//   bucket_emit (LDS scan -> rpq + cursors; 2 half-sweeps scatter to perm
//   with norm fused; no LDS staging, no per-edge global atomics).
// ---------------------------------------------------------------------------

__device__ inline int2 ldnt2(const int2* p) {
    long long v = __builtin_nontemporal_load((const long long*)p);
    int2 r;
    r.x = (int)(unsigned)(v & 0xFFFFFFFFLL);
    r.y = (int)(unsigned)((unsigned long long)v >> 32);
    return r;
}

typedef float __attribute__((ext_vector_type(4))) f4v;
__device__ inline float4 ldnt4(const float4* p) {
    f4v v = __builtin_nontemporal_load((const f4v*)p);
    float4 r;
    r.x = v.x; r.y = v.y; r.z = v.z; r.w = v.w;
    return r;
}

__device__ inline int quarter_of(int s, int qs) {
    return (s >= qs) + (s >= 2 * qs) + (s >= 3 * qs);
}

// ---- Pass A: per-bucket edge counts. bucket = dst >> 8 (256 nodes).
__global__ void __launch_bounds__(256) bucket_hist(const int* __restrict__ dst,
                                                   int* __restrict__ bcnt,
                                                   int E, int chunk) {
    __shared__ int h[512];
    for (int i = threadIdx.x; i < 512; i += 256) h[i] = 0;
    __syncthreads();
    int c0 = blockIdx.x * chunk;
    int c1 = min(E, c0 + chunk);
    for (int i = c0 + threadIdx.x; i < c1; i += 256)
        atomicAdd(&h[((unsigned)dst[i]) >> 8], 1);
    __syncthreads();
    for (int i = threadIdx.x; i < 512; i += 256)
        if (h[i]) atomicAdd(&bcnt[i], h[i]);
}

// ---- Pass B: scan 512 bins -> boff[513], gcur.
__global__ void __launch_bounds__(512) bucket_scan(const int* __restrict__ bcnt,
                                                   int* __restrict__ boff,
                                                   int* __restrict__ gcur) {
    __shared__ int part[512];
    int t = threadIdx.x;
    int c = bcnt[t];
    part[t] = c;
    __syncthreads();
    for (int off = 1; off < 512; off <<= 1) {
        int v = part[t];
        int a = (t >= off) ? part[t - off] : 0;
        __syncthreads();
        part[t] = v + a;
        __syncthreads();
    }
    int excl = part[t] - c;
    boff[t] = excl;
    gcur[t] = excl;
    if (t == 511) boff[512] = part[511];
}

// ---- Pass C: LDS counting-sort of 4096-edge tiles into bucket regions.
// pack: (local_dst(8b) << 24) | src(24b)
__global__ void __launch_bounds__(512) bucket_scatter(const int* __restrict__ src,
                                                      const int* __restrict__ dst,
                                                      const float* __restrict__ w,
                                                      int* __restrict__ gcur,
                                                      int2* __restrict__ bedge,
                                                      int E) {
    constexpr int TILE = 4096;
    __shared__ int hc[512];     // histogram, then cursor
    __shared__ int gb[512];
    __shared__ int part[512];
    __shared__ int2 sedge[TILE];
    __shared__ unsigned short sbuck[TILE];

    int t = threadIdx.x;
    int c0 = blockIdx.x * TILE;
    int mtile = min(TILE, E - c0);

    hc[t] = 0;
    __syncthreads();

    int  my_d[8];
    int  my_s[8];
    float my_w[8];
#pragma unroll
    for (int k = 0; k < 2; ++k) {
        int e0 = c0 + (t + k * 512) * 4;
        if (e0 + 4 <= E) {
            int4 d4 = *(const int4*)(dst + e0);
            int4 s4 = *(const int4*)(src + e0);
            float4 w4 = *(const float4*)(w + e0);
            my_d[k*4+0]=d4.x; my_d[k*4+1]=d4.y; my_d[k*4+2]=d4.z; my_d[k*4+3]=d4.w;
            my_s[k*4+0]=s4.x; my_s[k*4+1]=s4.y; my_s[k*4+2]=s4.z; my_s[k*4+3]=s4.w;
            my_w[k*4+0]=w4.x; my_w[k*4+1]=w4.y; my_w[k*4+2]=w4.z; my_w[k*4+3]=w4.w;
        } else {
#pragma unroll
            for (int j = 0; j < 4; ++j) {
                int e = e0 + j;
                bool ok = e < E;
                my_d[k*4+j] = ok ? dst[e] : -1;
                my_s[k*4+j] = ok ? src[e] : 0;
                my_w[k*4+j] = ok ? w[e] : 0.f;
            }
        }
    }
#pragma unroll
    for (int j = 0; j < 8; ++j)
        if (my_d[j] >= 0) atomicAdd(&hc[((unsigned)my_d[j]) >> 8], 1);
    __syncthreads();

    int hb = hc[t];
    part[t] = hb;
    __syncthreads();
    for (int off = 1; off < 512; off <<= 1) {
        int v = part[t];
        int a = (t >= off) ? part[t - off] : 0;
        __syncthreads();
        part[t] = v + a;
        __syncthreads();
    }
    int excl = part[t] - hb;
    hc[t] = excl;                                   // cursor = local offset
    gb[t] = hb ? (atomicAdd(&gcur[t], hb) - excl) : 0;
    __syncthreads();

#pragma unroll
    for (int j = 0; j < 8; ++j) {
        int d = my_d[j];
        if (d < 0) continue;
        unsigned ud = (unsigned)d;
        int b = ud >> 8;
        int p = atomicAdd(&hc[b], 1);
        sedge[p] = make_int2((int)(((ud & 255u) << 24) | (unsigned)my_s[j]),
                             __float_as_int(my_w[j]));
        sbuck[p] = (unsigned short)b;
    }
    __syncthreads();

    for (int i = t; i < mtile; i += 512) {
        int b = sbuck[i];
        bedge[gb[b] + i] = sedge[i];
    }
}

// ---- Pass D: per-bucket deg -> dinv ; per-(node,quarter) counts -> cntg, bq.
__global__ void __launch_bounds__(1024) bucket_stats(const int* __restrict__ boff,
                                                     const int2* __restrict__ bedge,
                                                     float* __restrict__ dinv,
                                                     int* __restrict__ cntg,
                                                     int* __restrict__ bq,
                                                     int N, int qs) {
    __shared__ float deg[256];
    __shared__ int cnt[1024];      // quarter-major: q*256 + local_node
    int b = blockIdx.x;
    int base = boff[b];
    int m = boff[b + 1] - base;
    int t = threadIdx.x;
    if (t < 256) deg[t] = 0.f;
    cnt[t] = 0;
    __syncthreads();
    for (int i = t; i < m; i += 1024) {
        int2 e = ldnt2(&bedge[base + i]);
        unsigned ux = (unsigned)e.x;
        int l = (int)(ux >> 24);
        int s = (int)(ux & 0xFFFFFFu);
        atomicAdd(&deg[l], __int_as_float(e.y));
        atomicAdd(&cnt[quarter_of(s, qs) * 256 + l], 1);
    }
    __syncthreads();
    int node = b * 256 + t;
    if (t < 256 && node < N) dinv[node] = rsqrtf(deg[t] + 1.0f);
    cntg[(size_t)b * 1024 + t] = cnt[t];
    if (t < 4) {
        int s = 0;
        for (int i = 0; i < 256; ++i) s += cnt[t * 256 + i];
        bq[b * 4 + t] = s;
    }
}

// ---- Pass E: scan bq in (q, bucket) order -> qbase[q*nbuck+b].
__global__ void __launch_bounds__(512) qscan(const int* __restrict__ bq,
                                             int* __restrict__ qbase, int nbuck) {
    __shared__ int part[512];
    int t = threadIdx.x;
    int TOT = 4 * nbuck;
    int C = (TOT + 511) / 512;
    int beg = t * C;
    int end = min(TOT, beg + C);
    if (beg > TOT) beg = TOT;
    int s = 0;
    for (int i = beg; i < end; ++i) {
        int q = i / nbuck, b = i - q * nbuck;
        s += bq[b * 4 + q];
    }
    part[t] = s;
    __syncthreads();
    for (int off = 1; off < 512; off <<= 1) {
        int v = part[t];
        int a = (t >= off) ? part[t - off] : 0;
        __syncthreads();
        part[t] = v + a;
        __syncthreads();
    }
    int run = part[t] - s;
    for (int i = beg; i < end; ++i) {
        int q = i / nbuck, b = i - q * nbuck;
        qbase[i] = run;
        run += bq[b * 4 + q];
    }
}

// ---- Pass F: rpq + scatter bedge -> perm (quarter-major), norm fused.
// Two half-sweeps (quarters 0,1 then 2,3): 512 cursor streams per block.
__global__ void __launch_bounds__(1024) bucket_emit(const int* __restrict__ boff,
                                                    const int2* __restrict__ bedge,
                                                    const int* __restrict__ cntg,
                                                    const int* __restrict__ qbase,
                                                    const float* __restrict__ dinv,
                                                    int2* __restrict__ perm,
                                                    int* __restrict__ rpq,
                                                    int N, int nbuck, int qs) {
    __shared__ int ofs[1024];
    __shared__ int cur[1024];
    __shared__ int part[1024];
    __shared__ float sdv[256];
    int b = blockIdx.x;
    int base = boff[b];
    int m = boff[b + 1] - base;
    int t = threadIdx.x;
    int c = cntg[(size_t)b * 1024 + t];
    if (t < 256) {
        int node = b * 256 + t;
        sdv[t] = (node < N) ? dinv[node] : 0.f;
    }
    part[t] = c;
    __syncthreads();
    for (int off = 1; off < 1024; off <<= 1) {
        int v = part[t];
        int a = (t >= off) ? part[t - off] : 0;
        __syncthreads();
        part[t] = v + a;
        __syncthreads();
    }
    int excl = part[t] - c;
    ofs[t] = excl;
    __syncthreads();
    int q = t >> 8;
    cur[t] = qbase[q * nbuck + b] + (excl - ofs[q * 256]);
    // per-quarter CSR rows
    if (t < 256) {
        int node = b * 256 + t;
        if (node < N) {
#pragma unroll
            for (int qq = 0; qq < 4; ++qq)
                rpq[(size_t)qq * (N + 1) + node] =
                    qbase[qq * nbuck + b] + (ofs[qq * 256 + t] - ofs[qq * 256]);
        }
    }
    if (b == nbuck - 1 && t < 4) {
        int qsz = ((t < 3) ? ofs[(t + 1) * 256] : m) - ofs[t * 256];
        rpq[(size_t)t * (N + 1) + N] = qbase[t * nbuck + b] + qsz;
    }
    __syncthreads();

    for (int sweep = 0; sweep < 2; ++sweep) {
        for (int i = t; i < m; i += 1024) {
            int2 e = ldnt2(&bedge[base + i]);
            unsigned ux = (unsigned)e.x;
            int l = (int)(ux >> 24);
            int s = (int)(ux & 0xFFFFFFu);
            int qr = quarter_of(s, qs);
            if ((qr >> 1) != sweep) continue;
            float nm = dinv[s] * __int_as_float(e.y) * sdv[l];
            int p = atomicAdd(&cur[qr * 256 + l], 1);
            perm[p] = make_int2(s, __float_as_int(nm));
        }
        __syncthreads();
    }
}

// x[N,256] @ W[256,16] -> xw[N,16].
__global__ void __launch_bounds__(256) gemm_x16(const float* __restrict__ x,
                                                const float* __restrict__ W,
                                                float* __restrict__ xw, int N) {
    __shared__ float Ws[256 * 16];
    for (int i = threadIdx.x; i < 256 * 16; i += 256) Ws[i] = W[i];
    __syncthreads();
    int c = threadIdx.x & 15;
    int rl = threadIdx.x >> 4;
    int r = blockIdx.x * 16 + rl;
    if (r >= N) return;
    const float4* x4 = (const float4*)(x + (size_t)r * 256);
    float acc = 0.f;
#pragma unroll 8
    for (int k4 = 0; k4 < 64; ++k4) {
        float4 v = ldnt4(x4 + k4);
        const float* wr = &Ws[k4 * 64 + c];
        acc += v.x * wr[0] + v.y * wr[16] + v.z * wr[32] + v.w * wr[48];
    }
    xw[(size_t)r * 16 + c] = acc;
}

// in[N,K] @ W[K,F] + bias -> out[N,F], optional ELU on output.
template <int K, int F, bool OUT_ELU>
__global__ void __launch_bounds__(256) gemm_small(const float* __restrict__ in,
                                                  const float* __restrict__ W,
                                                  const float* __restrict__ bias,
                                                  float* __restrict__ out, int N) {
    constexpr int ROWS = 256 / F;
    __shared__ float Ws[K * F];
    __shared__ float Is[ROWS * K];
    for (int i = threadIdx.x; i < K * F; i += 256) Ws[i] = W[i];
    int r0 = blockIdx.x * ROWS;
    for (int i = threadIdx.x; i < ROWS * K; i += 256)
        Is[i] = in[(size_t)r0 * K + i];
    __syncthreads();
    int c = threadIdx.x % F;
    int rl = threadIdx.x / F;
    float acc = bias[c];
#pragma unroll
    for (int k = 0; k < K; ++k) acc += Is[rl * K + k] * Ws[k * F + c];
    if (OUT_ELU) acc = acc > 0.f ? acc : expm1f(acc);
    out[(size_t)(r0 + rl) * F + c] = acc;
}

// ---- Quarter-phased register-accumulator gather-aggregate.
// One launch per phase (S quarters). flags: bit0 = init (self-loop [+bias]),
// bit1 = final (apply ELU if template ELU).
template <int F, int S, bool ELU>
__global__ void __launch_bounds__(256) agg_q(const int* __restrict__ rpq,
                                             const int2* __restrict__ perm,
                                             const float* __restrict__ xw,
                                             const float* __restrict__ dinv,
                                             const float* __restrict__ bias,
                                             float* __restrict__ out,
                                             int N, int q0, int flags) {
    constexpr int G = F / 4;
    constexpr int NPB = 256 / G;
    int node = blockIdx.x * NPB + threadIdx.x / G;
    int q = threadIdx.x % G;
    if (node >= N) return;
    const float4* xw4 = (const float4*)xw;
    float4* out4 = (float4*)out;
    float4 a0, a1, a2, a3;
    if (flags & 1) {
        float di = dinv[node];
        float d2 = di * di;
        float4 s = xw4[(size_t)node * G + q];
        a0.x = d2 * s.x; a0.y = d2 * s.y; a0.z = d2 * s.z; a0.w = d2 * s.w;
        if (bias) {
            float4 b4 = ((const float4*)bias)[q];
            a0.x += b4.x; a0.y += b4.y; a0.z += b4.z; a0.w += b4.w;
        }
    } else {
        a0 = out4[(size_t)node * G + q];
    }
    a1 = make_float4(0.f, 0.f, 0.f, 0.f);
    a2 = a1; a3 = a1;
#pragma unroll
    for (int ss = 0; ss < S; ++ss) {
        const int* rp = rpq + (size_t)(q0 + ss) * (N + 1);
        int j = rp[node];
        int je = rp[node + 1];
        for (; j + 3 < je; j += 4) {
            int2 p0 = ldnt2(perm + j);
            int2 p1 = ldnt2(perm + j + 1);
            int2 p2 = ldnt2(perm + j + 2);
            int2 p3 = ldnt2(perm + j + 3);
            float4 v0 = xw4[(size_t)p0.x * G + q];
            float4 v1 = xw4[(size_t)p1.x * G + q];
            float4 v2 = xw4[(size_t)p2.x * G + q];
            float4 v3 = xw4[(size_t)p3.x * G + q];
            float n0 = __int_as_float(p0.y);
            float n1 = __int_as_float(p1.y);
            float n2 = __int_as_float(p2.y);
            float n3 = __int_as_float(p3.y);
            a0.x += n0 * v0.x; a0.y += n0 * v0.y; a0.z += n0 * v0.z; a0.w += n0 * v0.w;
            a1.x += n1 * v1.x; a1.y += n1 * v1.y; a1.z += n1 * v1.z; a1.w += n1 * v1.w;
            a2.x += n2 * v2.x; a2.y += n2 * v2.y; a2.z += n2 * v2.z; a2.w += n2 * v2.w;
            a3.x += n3 * v3.x; a3.y += n3 * v3.y; a3.z += n3 * v3.z; a3.w += n3 * v3.w;
        }
        for (; j < je; ++j) {
            int2 p0 = ldnt2(perm + j);
            float4 v0 = xw4[(size_t)p0.x * G + q];
            float n0 = __int_as_float(p0.y);
            a0.x += n0 * v0.x; a0.y += n0 * v0.y; a0.z += n0 * v0.z; a0.w += n0 * v0.w;
        }
    }
    float4 r;
    r.x = (a0.x + a1.x) + (a2.x + a3.x);
    r.y = (a0.y + a1.y) + (a2.y + a3.y);
    r.z = (a0.z + a1.z) + (a2.z + a3.z);
    r.w = (a0.w + a1.w) + (a2.w + a3.w);
    if (ELU && (flags & 2)) {
        r.x = r.x > 0.f ? r.x : expm1f(r.x);
        r.y = r.y > 0.f ? r.y : expm1f(r.y);
        r.z = r.z > 0.f ? r.z : expm1f(r.z);
        r.w = r.w > 0.f ? r.w : expm1f(r.w);
    }
    out4[(size_t)node * G + q] = r;
}

extern "C" void kernel_launch(void* const* d_in, const int* in_sizes, int n_in,
                              void* d_out, int out_size, void* d_ws, size_t ws_size,
                              hipStream_t stream) {
    const float* x  = (const float*)d_in[0];
    const int*   ei = (const int*)d_in[1];
    const float* w  = (const float*)d_in[2];
    const float* W0 = (const float*)d_in[3];
    const float* b0 = (const float*)d_in[4];
    const float* W1 = (const float*)d_in[5];
    const float* b1 = (const float*)d_in[6];
    const float* W2 = (const float*)d_in[7];
    const float* b2 = (const float*)d_in[8];
    const float* Wm = (const float*)d_in[9];
    const float* bm = (const float*)d_in[10];
    float* out = (float*)d_out;

    const int N = in_sizes[0] / 256;
    const int E = in_sizes[2];
    const int* src = ei;
    const int* dst = ei + E;
    const int nbuck = (N + 255) >> 8;      // 256-node buckets (<=512)
    const int qs = (N + 3) / 4;            // src-quarter size

    char* ws = (char*)d_ws;
    size_t off = 0;
    auto alloc = [&](size_t bytes) {
        void* p = ws + off;
        off = (off + bytes + 255) & ~(size_t)255;
        return p;
    };
    float* dinv  = (float*)alloc((size_t)N * 4);
    int*   rpq   = (int*)alloc((size_t)4 * (N + 1) * 4);
    int*   bcnt  = (int*)alloc(520 * 4);
    int*   boff  = (int*)alloc(520 * 4);
    int*   gcur  = (int*)alloc(520 * 4);
    int*   bq    = (int*)alloc((size_t)nbuck * 4 * 4);
    int*   qbase = (int*)alloc((size_t)nbuck * 4 * 4);
    int*   cntg  = (int*)alloc((size_t)nbuck * 1024 * 4);
    int2*  bedge = (int2*)alloc((size_t)E * 8);
    int2*  perm  = (int2*)alloc((size_t)E * 8);
    float* BUF_A = (float*)alloc((size_t)N * 32 * 4);
    float* BUF_B = (float*)alloc((size_t)N * 32 * 4);

    hipMemsetAsync(bcnt, 0, 512 * 4, stream);

    // ---- build quarter-major CSR (layer-invariant)
    bucket_hist<<<(E + 8191) / 8192, 256, 0, stream>>>(dst, bcnt, E, 8192);
    bucket_scan<<<1, 512, 0, stream>>>(bcnt, boff, gcur);
    bucket_scatter<<<(E + 4095) / 4096, 512, 0, stream>>>(src, dst, w, gcur, bedge, E);
    bucket_stats<<<nbuck, 1024, 0, stream>>>(boff, bedge, dinv, cntg, bq, N, qs);
    qscan<<<1, 512, 0, stream>>>(bq, qbase, nbuck);
    bucket_emit<<<nbuck, 1024, 0, stream>>>(boff, bedge, cntg, qbase, dinv, perm, rpq, N, nbuck, qs);

    // ---- layer 0: XW = x@W0 ; h1 = elu(A.XW + b0)   [2 phases x 2 quarters]
    gemm_x16<<<(N + 15) / 16, 256, 0, stream>>>(x, W0, BUF_A, N);
    agg_q<16, 2, true><<<(N + 63) / 64, 256, 0, stream>>>(rpq, perm, BUF_A, dinv, b0, BUF_B, N, 0, 1);
    agg_q<16, 2, true><<<(N + 63) / 64, 256, 0, stream>>>(rpq, perm, BUF_A, dinv, b0, BUF_B, N, 2, 2);

    // ---- layer 1: AG1 = A.h1 ; h2 = elu(AG1@W1 + b1)
    agg_q<16, 2, false><<<(N + 63) / 64, 256, 0, stream>>>(rpq, perm, BUF_B, dinv, nullptr, BUF_A, N, 0, 1);
    agg_q<16, 2, false><<<(N + 63) / 64, 256, 0, stream>>>(rpq, perm, BUF_B, dinv, nullptr, BUF_A, N, 2, 0);
    gemm_small<16, 32, true><<<(N + 7) / 8, 256, 0, stream>>>(BUF_A, W1, b1, BUF_B, N);

    // ---- layer 2: AG2 = A.h2 ; h3 = elu(AG2@W2 + b2)  [4 phases x 1 quarter]
    agg_q<32, 1, false><<<(N + 31) / 32, 256, 0, stream>>>(rpq, perm, BUF_B, dinv, nullptr, BUF_A, N, 0, 1);
    agg_q<32, 1, false><<<(N + 31) / 32, 256, 0, stream>>>(rpq, perm, BUF_B, dinv, nullptr, BUF_A, N, 1, 0);
    agg_q<32, 1, false><<<(N + 31) / 32, 256, 0, stream>>>(rpq, perm, BUF_B, dinv, nullptr, BUF_A, N, 2, 0);
    agg_q<32, 1, false><<<(N + 31) / 32, 256, 0, stream>>>(rpq, perm, BUF_B, dinv, nullptr, BUF_A, N, 3, 0);
    gemm_small<32, 32, true><<<(N + 7) / 8, 256, 0, stream>>>(BUF_A, W2, b2, BUF_B, N);

    // ---- head: out = h3@Wm + bm
    gemm_small<32, 16, false><<<(N + 15) / 16, 256, 0, stream>>>(BUF_B, Wm, bm, out, N);
}